// Round 1
// baseline (1678.076 us; speedup 1.0000x reference)
//
#include <hip/hip_runtime.h>

// Problem constants (fixed by the reference setup)
constexpr int NN = 100000;   // nodes
constexpr int RR = 8;        // relations
constexpr int BB = 4;        // bases
constexpr int DD = 64;       // feature dim
constexpr int EE = 2000000;  // edges
constexpr int PP = 500000;   // pairs

// ---------------------------------------------------------------------------
// Count edges per (dst, relation) segment. cnt is float (exact for ints<2^24).
__global__ void count_kernel(const int* __restrict__ dst, const int* __restrict__ et,
                             float* __restrict__ cnt) {
    int e = blockIdx.x * blockDim.x + threadIdx.x;
    if (e < EE) atomicAdd(&cnt[dst[e] * RR + et[e]], 1.0f);
}

// ---------------------------------------------------------------------------
// W[r,i,o] = sum_b comp[r,b] * basis[b,i,o]
__global__ void compw_kernel(const float* __restrict__ comp, const float* __restrict__ basis,
                             float* __restrict__ W) {
    int idx = blockIdx.x * blockDim.x + threadIdx.x;
    if (idx >= RR * DD * DD) return;
    int r = idx >> 12;          // / (64*64)
    int io = idx & 4095;
    float acc = 0.f;
#pragma unroll
    for (int b = 0; b < BB; ++b) acc += comp[r * BB + b] * basis[b * 4096 + io];
    W[idx] = acc;
}

// ---------------------------------------------------------------------------
// One wave per edge: mean[(v,r),:] += x[u,:] / max(cnt[v,r],1)
__global__ void scatter_kernel(const int* __restrict__ src, const int* __restrict__ dst,
                               const int* __restrict__ et, const float* __restrict__ x,
                               const float* __restrict__ cnt, float* __restrict__ mean) {
    int e = blockIdx.x * 4 + (threadIdx.x >> 6);
    int lane = threadIdx.x & 63;
    if (e >= EE) return;
    int u = src[e], v = dst[e], r = et[e];
    float inv = 1.0f / fmaxf(cnt[v * RR + r], 1.0f);
    atomicAdd(&mean[(v * RR + r) * DD + lane], x[u * DD + lane] * inv);
}

// ---------------------------------------------------------------------------
// out[n,o] = bias[o] + sum_i xin[n,i]*root[i,o] + sum_{r,i} mean[n,r,i]*W[r,i,o]
// Block = 256 threads = 4 waves, each wave owns 8 nodes (32 nodes/block).
// Feat values broadcast from LDS (per-wave region -> no barriers needed),
// weight rows are coalesced across lanes and L1-resident.
template <int RELU>
__global__ void combine_kernel(const float* __restrict__ xin, const float* __restrict__ mean,
                               const float* __restrict__ W, const float* __restrict__ root,
                               const float* __restrict__ bias, float* __restrict__ out) {
    __shared__ float xs[32 * 64];
    __shared__ float ms[32 * 64];
    int lane = threadIdx.x & 63;
    int wid = threadIdx.x >> 6;
    int nb = blockIdx.x * 32 + wid * 8;  // first node of this wave

#pragma unroll
    for (int q = 0; q < 8; ++q)
        xs[(wid * 8 + q) * 64 + lane] = xin[(size_t)(nb + q) * 64 + lane];

    float bv = bias[lane];
    float acc[8];
#pragma unroll
    for (int q = 0; q < 8; ++q) acc[q] = bv;

    // root (self) transform
    for (int i = 0; i < 64; i += 4) {
        float4 f[8];
#pragma unroll
        for (int q = 0; q < 8; ++q)
            f[q] = *reinterpret_cast<const float4*>(&xs[(wid * 8 + q) * 64 + i]);
#pragma unroll
        for (int j = 0; j < 4; ++j) {
            float w = root[(i + j) * 64 + lane];
#pragma unroll
            for (int q = 0; q < 8; ++q)
                acc[q] += reinterpret_cast<const float*>(&f[q])[j] * w;
        }
    }

    // relation transforms
    for (int r = 0; r < RR; ++r) {
#pragma unroll
        for (int q = 0; q < 8; ++q)
            ms[(wid * 8 + q) * 64 + lane] =
                mean[((size_t)(nb + q) * RR + r) * 64 + lane];
        const float* Wr = W + r * 4096;
        for (int i = 0; i < 64; i += 4) {
            float4 f[8];
#pragma unroll
            for (int q = 0; q < 8; ++q)
                f[q] = *reinterpret_cast<const float4*>(&ms[(wid * 8 + q) * 64 + i]);
#pragma unroll
            for (int j = 0; j < 4; ++j) {
                float w = Wr[(i + j) * 64 + lane];
#pragma unroll
                for (int q = 0; q < 8; ++q)
                    acc[q] += reinterpret_cast<const float*>(&f[q])[j] * w;
            }
        }
    }

#pragma unroll
    for (int q = 0; q < 8; ++q) {
        float v = acc[q];
        if (RELU) v = fmaxf(v, 0.f);
        out[(size_t)(nb + q) * 64 + lane] = v;
    }
}

// ---------------------------------------------------------------------------
// ha[n,:] = z[n,:] @ W1[0:64,:]   hb[n,:] = z[n,:] @ W1[64:128,:]
// (decoder concat-GEMM split: feat@W1 = z[a]@W1_top + z[b]@W1_bot)
__global__ void project_kernel(const float* __restrict__ z, const float* __restrict__ W1,
                               float* __restrict__ ha, float* __restrict__ hb) {
    __shared__ float w1s[128 * 64];  // 32 KB
    __shared__ float zs[32 * 64];    // 8 KB
    int lane = threadIdx.x & 63;
    int wid = threadIdx.x >> 6;
    for (int t = threadIdx.x; t < 128 * 64; t += 256) w1s[t] = W1[t];
    int nb = blockIdx.x * 32 + wid * 8;
#pragma unroll
    for (int q = 0; q < 8; ++q)
        zs[(wid * 8 + q) * 64 + lane] = z[(size_t)(nb + q) * 64 + lane];
    __syncthreads();

    float accA[8], accB[8];
#pragma unroll
    for (int q = 0; q < 8; ++q) { accA[q] = 0.f; accB[q] = 0.f; }

    for (int i = 0; i < 64; i += 4) {
        float4 f[8];
#pragma unroll
        for (int q = 0; q < 8; ++q)
            f[q] = *reinterpret_cast<const float4*>(&zs[(wid * 8 + q) * 64 + i]);
#pragma unroll
        for (int j = 0; j < 4; ++j) {
            float wA = w1s[(i + j) * 64 + lane];
            float wB = w1s[(64 + i + j) * 64 + lane];
#pragma unroll
            for (int q = 0; q < 8; ++q) {
                float fv = reinterpret_cast<const float*>(&f[q])[j];
                accA[q] += fv * wA;
                accB[q] += fv * wB;
            }
        }
    }
#pragma unroll
    for (int q = 0; q < 8; ++q) {
        ha[(size_t)(nb + q) * 64 + lane] = accA[q];
        hb[(size_t)(nb + q) * 64 + lane] = accB[q];
    }
}

// ---------------------------------------------------------------------------
// logit[p] = (relu(ha[a]+hb[b]+b1) . W2) + b2 — one wave per pair
__global__ void decode_kernel(const int* __restrict__ pairs, const float* __restrict__ ha,
                              const float* __restrict__ hb, const float* __restrict__ b1,
                              const float* __restrict__ W2, const float* __restrict__ b2,
                              float* __restrict__ out) {
    int lane = threadIdx.x & 63;
    int wid = threadIdx.x >> 6;
    int p = blockIdx.x * 4 + wid;
    if (p >= PP) return;
    int a = pairs[2 * p], b = pairs[2 * p + 1];
    float v = ha[(size_t)a * 64 + lane] + hb[(size_t)b * 64 + lane] + b1[lane];
    v = fmaxf(v, 0.f) * W2[lane];
#pragma unroll
    for (int off = 32; off >= 1; off >>= 1) v += __shfl_xor(v, off);
    if (lane == 0) out[p] = v + b2[0];
}

// ---------------------------------------------------------------------------
extern "C" void kernel_launch(void* const* d_in, const int* in_sizes, int n_in,
                              void* d_out, int out_size, void* d_ws, size_t ws_size,
                              hipStream_t stream) {
    const int* edge_index = (const int*)d_in[0];
    const int* edge_type  = (const int*)d_in[1];
    const int* edge_pairs = (const int*)d_in[2];
    const float* node_emb = (const float*)d_in[3];
    const float* comp1 = (const float*)d_in[4];
    const float* basis1 = (const float*)d_in[5];
    const float* root1 = (const float*)d_in[6];
    const float* bias1 = (const float*)d_in[7];
    const float* comp2 = (const float*)d_in[8];
    const float* basis2 = (const float*)d_in[9];
    const float* root2 = (const float*)d_in[10];
    const float* bias2 = (const float*)d_in[11];
    const float* W1 = (const float*)d_in[12];
    const float* b1 = (const float*)d_in[13];
    const float* W2 = (const float*)d_in[14];
    const float* b2 = (const float*)d_in[15];

    const int* src = edge_index;
    const int* dst = edge_index + EE;

    // workspace layout (floats): cnt | Wbuf | x1 | z | mean  (~259.3 MB total)
    float* w    = (float*)d_ws;
    float* cnt  = w;                            // N*R       = 800,000
    float* Wbuf = cnt + (size_t)NN * RR;        // R*D*D     = 32,768
    float* x1   = Wbuf + RR * DD * DD;          // N*D       = 6,400,000
    float* z    = x1 + (size_t)NN * DD;         // N*D       = 6,400,000
    float* mean = z + (size_t)NN * DD;          // N*R*D     = 51,200,000
    float* ha   = mean;                         // reuse mean buffer after layer 2
    float* hb   = mean + (size_t)NN * DD;

    // counts (shared by both layers — graph is the same)
    hipMemsetAsync(cnt, 0, (size_t)NN * RR * sizeof(float), stream);
    count_kernel<<<(EE + 255) / 256, 256, 0, stream>>>(dst, edge_type, cnt);

    // ---- layer 1: node_emb -> x1 (relu) ----
    compw_kernel<<<(RR * DD * DD + 255) / 256, 256, 0, stream>>>(comp1, basis1, Wbuf);
    hipMemsetAsync(mean, 0, (size_t)NN * RR * DD * sizeof(float), stream);
    scatter_kernel<<<EE / 4, 256, 0, stream>>>(src, dst, edge_type, node_emb, cnt, mean);
    combine_kernel<1><<<NN / 32, 256, 0, stream>>>(node_emb, mean, Wbuf, root1, bias1, x1);

    // ---- layer 2: x1 -> z ----
    compw_kernel<<<(RR * DD * DD + 255) / 256, 256, 0, stream>>>(comp2, basis2, Wbuf);
    hipMemsetAsync(mean, 0, (size_t)NN * RR * DD * sizeof(float), stream);
    scatter_kernel<<<EE / 4, 256, 0, stream>>>(src, dst, edge_type, x1, cnt, mean);
    combine_kernel<0><<<NN / 32, 256, 0, stream>>>(x1, mean, Wbuf, root2, bias2, z);

    // ---- decoder ----
    project_kernel<<<NN / 32, 256, 0, stream>>>(z, W1, ha, hb);
    decode_kernel<<<PP / 4, 256, 0, stream>>>(edge_pairs, ha, hb, b1, W2, b2, (float*)d_out);
}

// Round 2
// 1437.300 us; speedup vs baseline: 1.1675x; 1.1675x over previous
//
#include <hip/hip_runtime.h>

// Problem constants (fixed by the reference setup)
constexpr int NN = 100000;   // nodes
constexpr int RR = 8;        // relations
constexpr int BB = 4;        // bases
constexpr int DD = 64;       // feature dim
constexpr int EE = 2000000;  // edges
constexpr int PP = 500000;   // pairs
constexpr int NR = NN * RR;  // segments = 800000

constexpr int SCAN_CHUNK = 1024;
constexpr int NBLK = (NR + SCAN_CHUNK - 1) / SCAN_CHUNK;  // 782

// ---------------------------------------------------------------------------
// integer counts per (dst, relation) segment
__global__ void count_kernel(const int* __restrict__ dst, const int* __restrict__ et,
                             int* __restrict__ cnt) {
    int e = blockIdx.x * blockDim.x + threadIdx.x;
    if (e < EE) atomicAdd(&cnt[dst[e] * RR + et[e]], 1);
}

// K1: per-block sums of 1024-element chunks
__global__ void scan_sums(const int* __restrict__ cnt, int* __restrict__ bsum) {
    __shared__ int sh[256];
    int base = blockIdx.x * SCAN_CHUNK;
    int t = threadIdx.x;
    int s = 0;
    for (int i = t; i < SCAN_CHUNK; i += 256) {
        int idx = base + i;
        s += (idx < NR) ? cnt[idx] : 0;
    }
    sh[t] = s;
    __syncthreads();
    for (int off = 128; off >= 1; off >>= 1) {
        if (t < off) sh[t] += sh[t + off];
        __syncthreads();
    }
    if (t == 0) bsum[blockIdx.x] = sh[0];
}

// K2: single-block exclusive scan of the NBLK partials
__global__ void scan_partials(int* __restrict__ bsum) {
    __shared__ int sh[1024];
    int t = threadIdx.x;
    int orig = (t < NBLK) ? bsum[t] : 0;
    sh[t] = orig;
    __syncthreads();
    for (int off = 1; off < 1024; off <<= 1) {
        int v = (t >= off) ? sh[t - off] : 0;
        __syncthreads();
        sh[t] += v;
        __syncthreads();
    }
    if (t < NBLK) bsum[t] = sh[t] - orig;  // exclusive
}

// K3: final exclusive scan, writes offs[] and cursor[] (fill scratch)
__global__ void scan_final(const int* __restrict__ cnt, const int* __restrict__ bsum,
                           int* __restrict__ offs, int* __restrict__ cursor) {
    __shared__ int sh[256];
    int base = blockIdx.x * SCAN_CHUNK;
    int t = threadIdx.x;
    int idx0 = base + t * 4;
    int v[4];
    int s = 0;
#pragma unroll
    for (int j = 0; j < 4; ++j) {
        int idx = idx0 + j;
        v[j] = (idx < NR) ? cnt[idx] : 0;
        s += v[j];
    }
    int orig = s;
    sh[t] = s;
    __syncthreads();
    for (int off = 1; off < 256; off <<= 1) {
        int u = (t >= off) ? sh[t - off] : 0;
        __syncthreads();
        sh[t] += u;
        __syncthreads();
    }
    int tbase = bsum[blockIdx.x] + sh[t] - orig;
#pragma unroll
    for (int j = 0; j < 4; ++j) {
        int idx = idx0 + j;
        if (idx < NR) {
            offs[idx] = tbase;
            cursor[idx] = tbase;
        }
        tbase += v[j];
    }
    if (blockIdx.x == 0 && t == 0) offs[NR] = EE;
}

// fill: scatter src node ids into segment-sorted order
__global__ void fill_kernel(const int* __restrict__ src, const int* __restrict__ dst,
                            const int* __restrict__ et, int* __restrict__ cursor,
                            int* __restrict__ esrc) {
    int e = blockIdx.x * blockDim.x + threadIdx.x;
    if (e >= EE) return;
    int pos = atomicAdd(&cursor[dst[e] * RR + et[e]], 1);
    esrc[pos] = src[e];
}

// ---------------------------------------------------------------------------
// W[r,i,o] = sum_b comp[r,b] * basis[b,i,o]
__global__ void compw_kernel(const float* __restrict__ comp, const float* __restrict__ basis,
                             float* __restrict__ W) {
    int idx = blockIdx.x * blockDim.x + threadIdx.x;
    if (idx >= RR * DD * DD) return;
    int r = idx >> 12;
    int io = idx & 4095;
    float acc = 0.f;
#pragma unroll
    for (int b = 0; b < BB; ++b) acc += comp[r * BB + b] * basis[b * 4096 + io];
    W[idx] = acc;
}

// ---------------------------------------------------------------------------
// Fused per-layer kernel: CSR aggregation (mean per (node,rel)) + W_r transform
// + root transform + bias (+ optional ReLU). Block = 4 waves, wave owns 8 nodes.
template <int RELU>
__global__ void rgcn_fused(const float* __restrict__ xin, const int* __restrict__ esrc,
                           const int* __restrict__ offs, const float* __restrict__ W,
                           const float* __restrict__ root, const float* __restrict__ bias,
                           float* __restrict__ out) {
    __shared__ float xs[32 * 64];
    __shared__ float ms[32 * 64];
    int lane = threadIdx.x & 63;
    int wid = threadIdx.x >> 6;
    int nb = blockIdx.x * 32 + wid * 8;  // first node of this wave

    // coalesced load of the 65 segment offsets this wave needs
    int obase = nb * RR;                       // 64 segments for 8 nodes
    int o_l = offs[obase + lane];
    int o_end = offs[obase + 64];

#pragma unroll
    for (int q = 0; q < 8; ++q)
        xs[(wid * 8 + q) * 64 + lane] = xin[(size_t)(nb + q) * 64 + lane];

    float bv = bias[lane];
    float acc[8];
#pragma unroll
    for (int q = 0; q < 8; ++q) acc[q] = bv;

    // root (self) transform
    for (int i = 0; i < 64; i += 4) {
        float4 f[8];
#pragma unroll
        for (int q = 0; q < 8; ++q)
            f[q] = *reinterpret_cast<const float4*>(&xs[(wid * 8 + q) * 64 + i]);
#pragma unroll
        for (int j = 0; j < 4; ++j) {
            float w = root[(i + j) * 64 + lane];
#pragma unroll
            for (int q = 0; q < 8; ++q)
                acc[q] += reinterpret_cast<const float*>(&f[q])[j] * w;
        }
    }

    // relation transforms, aggregation fused
    for (int r = 0; r < RR; ++r) {
#pragma unroll
        for (int q = 0; q < 8; ++q) {
            int si = q * RR + r;
            int s0 = __shfl(o_l, si);
            int s1 = (si < 63) ? __shfl(o_l, si + 1) : o_end;
            float s = 0.f;
            int k = s0;
            for (; k + 1 < s1; k += 2) {
                int u0 = esrc[k], u1 = esrc[k + 1];
                s += xin[(size_t)u0 * 64 + lane];
                s += xin[(size_t)u1 * 64 + lane];
            }
            if (k < s1) s += xin[(size_t)esrc[k] * 64 + lane];
            float inv = (s1 > s0) ? 1.f / (float)(s1 - s0) : 0.f;
            ms[(wid * 8 + q) * 64 + lane] = s * inv;
        }
        const float* Wr = W + r * 4096;
        for (int i = 0; i < 64; i += 4) {
            float4 f[8];
#pragma unroll
            for (int q = 0; q < 8; ++q)
                f[q] = *reinterpret_cast<const float4*>(&ms[(wid * 8 + q) * 64 + i]);
#pragma unroll
            for (int j = 0; j < 4; ++j) {
                float w = Wr[(i + j) * 64 + lane];
#pragma unroll
                for (int q = 0; q < 8; ++q)
                    acc[q] += reinterpret_cast<const float*>(&f[q])[j] * w;
            }
        }
    }

#pragma unroll
    for (int q = 0; q < 8; ++q) {
        float v = acc[q];
        if (RELU) v = fmaxf(v, 0.f);
        out[(size_t)(nb + q) * 64 + lane] = v;
    }
}

// ---------------------------------------------------------------------------
// ha[n,:] = z[n,:] @ W1[0:64,:]   hb[n,:] = z[n,:] @ W1[64:128,:]
__global__ void project_kernel(const float* __restrict__ z, const float* __restrict__ W1,
                               float* __restrict__ ha, float* __restrict__ hb) {
    __shared__ float w1s[128 * 64];
    __shared__ float zs[32 * 64];
    int lane = threadIdx.x & 63;
    int wid = threadIdx.x >> 6;
    for (int t = threadIdx.x; t < 128 * 64; t += 256) w1s[t] = W1[t];
    int nb = blockIdx.x * 32 + wid * 8;
#pragma unroll
    for (int q = 0; q < 8; ++q)
        zs[(wid * 8 + q) * 64 + lane] = z[(size_t)(nb + q) * 64 + lane];
    __syncthreads();

    float accA[8], accB[8];
#pragma unroll
    for (int q = 0; q < 8; ++q) { accA[q] = 0.f; accB[q] = 0.f; }

    for (int i = 0; i < 64; i += 4) {
        float4 f[8];
#pragma unroll
        for (int q = 0; q < 8; ++q)
            f[q] = *reinterpret_cast<const float4*>(&zs[(wid * 8 + q) * 64 + i]);
#pragma unroll
        for (int j = 0; j < 4; ++j) {
            float wA = w1s[(i + j) * 64 + lane];
            float wB = w1s[(64 + i + j) * 64 + lane];
#pragma unroll
            for (int q = 0; q < 8; ++q) {
                float fv = reinterpret_cast<const float*>(&f[q])[j];
                accA[q] += fv * wA;
                accB[q] += fv * wB;
            }
        }
    }
#pragma unroll
    for (int q = 0; q < 8; ++q) {
        ha[(size_t)(nb + q) * 64 + lane] = accA[q];
        hb[(size_t)(nb + q) * 64 + lane] = accB[q];
    }
}

// ---------------------------------------------------------------------------
// logit[p] = (relu(ha[a]+hb[b]+b1) . W2) + b2 — one wave per pair
__global__ void decode_kernel(const int* __restrict__ pairs, const float* __restrict__ ha,
                              const float* __restrict__ hb, const float* __restrict__ b1,
                              const float* __restrict__ W2, const float* __restrict__ b2,
                              float* __restrict__ out) {
    int lane = threadIdx.x & 63;
    int wid = threadIdx.x >> 6;
    int p = blockIdx.x * 4 + wid;
    if (p >= PP) return;
    int a = pairs[2 * p], b = pairs[2 * p + 1];
    float v = ha[(size_t)a * 64 + lane] + hb[(size_t)b * 64 + lane] + b1[lane];
    v = fmaxf(v, 0.f) * W2[lane];
#pragma unroll
    for (int off = 32; off >= 1; off >>= 1) v += __shfl_xor(v, off);
    if (lane == 0) out[p] = v + b2[0];
}

// ---------------------------------------------------------------------------
extern "C" void kernel_launch(void* const* d_in, const int* in_sizes, int n_in,
                              void* d_out, int out_size, void* d_ws, size_t ws_size,
                              hipStream_t stream) {
    const int* edge_index = (const int*)d_in[0];
    const int* edge_type  = (const int*)d_in[1];
    const int* edge_pairs = (const int*)d_in[2];
    const float* node_emb = (const float*)d_in[3];
    const float* comp1 = (const float*)d_in[4];
    const float* basis1 = (const float*)d_in[5];
    const float* root1 = (const float*)d_in[6];
    const float* bias1 = (const float*)d_in[7];
    const float* comp2 = (const float*)d_in[8];
    const float* basis2 = (const float*)d_in[9];
    const float* root2 = (const float*)d_in[10];
    const float* bias2 = (const float*)d_in[11];
    const float* W1 = (const float*)d_in[12];
    const float* b1 = (const float*)d_in[13];
    const float* W2 = (const float*)d_in[14];
    const float* b2 = (const float*)d_in[15];

    const int* src = edge_index;
    const int* dst = edge_index + EE;

    // workspace layout
    char* w = (char*)d_ws;
    int* cnt    = (int*)w;                     w += sizeof(int) * NR;        // 3.2 MB
    int* bsum   = (int*)w;                     w += sizeof(int) * 1024;
    int* offs   = (int*)w;                     w += sizeof(int) * (NR + 1);
    int* cursor = (int*)w;                     w += sizeof(int) * (NR + 1);
    int* esrc   = (int*)w;                     w += sizeof(int) * EE;        // 8 MB
    float* Wbuf = (float*)w;                   w += sizeof(float) * RR * DD * DD;
    float* x1   = (float*)w;                   w += sizeof(float) * (size_t)NN * DD;  // 25.6 MB
    float* z    = (float*)w;                   w += sizeof(float) * (size_t)NN * DD;
    float* ha   = (float*)w;                   w += sizeof(float) * (size_t)NN * DD;
    float* hb   = (float*)w;                   w += sizeof(float) * (size_t)NN * DD;

    // ---- CSR build (graph is shared by both layers) ----
    hipMemsetAsync(cnt, 0, sizeof(int) * NR, stream);
    count_kernel<<<(EE + 255) / 256, 256, 0, stream>>>(dst, edge_type, cnt);
    scan_sums<<<NBLK, 256, 0, stream>>>(cnt, bsum);
    scan_partials<<<1, 1024, 0, stream>>>(bsum);
    scan_final<<<NBLK, 256, 0, stream>>>(cnt, bsum, offs, cursor);
    fill_kernel<<<(EE + 255) / 256, 256, 0, stream>>>(src, dst, edge_type, cursor, esrc);

    // ---- layer 1: node_emb -> x1 (relu) ----
    compw_kernel<<<(RR * DD * DD + 255) / 256, 256, 0, stream>>>(comp1, basis1, Wbuf);
    rgcn_fused<1><<<NN / 32, 256, 0, stream>>>(node_emb, esrc, offs, Wbuf, root1, bias1, x1);

    // ---- layer 2: x1 -> z ----
    compw_kernel<<<(RR * DD * DD + 255) / 256, 256, 0, stream>>>(comp2, basis2, Wbuf);
    rgcn_fused<0><<<NN / 32, 256, 0, stream>>>(x1, esrc, offs, Wbuf, root2, bias2, z);

    // ---- decoder ----
    project_kernel<<<NN / 32, 256, 0, stream>>>(z, W1, ha, hb);
    decode_kernel<<<PP / 4, 256, 0, stream>>>(edge_pairs, ha, hb, b1, W2, b2, (float*)d_out);
}

// Round 3
// 1323.404 us; speedup vs baseline: 1.2680x; 1.0861x over previous
//
#include <hip/hip_runtime.h>

// Problem constants (fixed by the reference setup)
constexpr int NN = 100000;   // nodes
constexpr int RR = 8;        // relations
constexpr int BB = 4;        // bases
constexpr int DD = 64;       // feature dim
constexpr int EE = 2000000;  // edges
constexpr int PP = 500000;   // pairs

constexpr int SCAN_CHUNK = 1024;
constexpr int NBLKN = (NN + SCAN_CHUNK - 1) / SCAN_CHUNK;  // 98

// ---------------------------------------------------------------------------
// integer counts per (dst, relation) cell
__global__ void count_kernel(const int* __restrict__ dst, const int* __restrict__ et,
                             int* __restrict__ cnt) {
    int e = blockIdx.x * blockDim.x + threadIdx.x;
    if (e < EE) atomicAdd(&cnt[dst[e] * RR + et[e]], 1);
}

// node degree = sum of its 8 relation counts
__global__ void deg_kernel(const int* __restrict__ cnt, int* __restrict__ deg) {
    int n = blockIdx.x * blockDim.x + threadIdx.x;
    if (n >= NN) return;
    const int4* c = reinterpret_cast<const int4*>(cnt + n * 8);
    int4 a = c[0], b = c[1];
    deg[n] = a.x + a.y + a.z + a.w + b.x + b.y + b.z + b.w;
}

// K1: per-block sums of 1024-element chunks of deg
__global__ void scan_sums(const int* __restrict__ deg, int* __restrict__ bsum) {
    __shared__ int sh[256];
    int base = blockIdx.x * SCAN_CHUNK;
    int t = threadIdx.x;
    int s = 0;
    for (int i = t; i < SCAN_CHUNK; i += 256) {
        int idx = base + i;
        s += (idx < NN) ? deg[idx] : 0;
    }
    sh[t] = s;
    __syncthreads();
    for (int off = 128; off >= 1; off >>= 1) {
        if (t < off) sh[t] += sh[t + off];
        __syncthreads();
    }
    if (t == 0) bsum[blockIdx.x] = sh[0];
}

// K2: single-block exclusive scan of the NBLKN partials
__global__ void scan_partials(int* __restrict__ bsum) {
    __shared__ int sh[1024];
    int t = threadIdx.x;
    int orig = (t < NBLKN) ? bsum[t] : 0;
    sh[t] = orig;
    __syncthreads();
    for (int off = 1; off < 1024; off <<= 1) {
        int v = (t >= off) ? sh[t - off] : 0;
        __syncthreads();
        sh[t] += v;
        __syncthreads();
    }
    if (t < NBLKN) bsum[t] = sh[t] - orig;  // exclusive
}

// K3: final exclusive scan -> noffs[] and cursor[]
__global__ void scan_final(const int* __restrict__ deg, const int* __restrict__ bsum,
                           int* __restrict__ noffs, int* __restrict__ cursor) {
    __shared__ int sh[256];
    int base = blockIdx.x * SCAN_CHUNK;
    int t = threadIdx.x;
    int idx0 = base + t * 4;
    int v[4];
    int s = 0;
#pragma unroll
    for (int j = 0; j < 4; ++j) {
        int idx = idx0 + j;
        v[j] = (idx < NN) ? deg[idx] : 0;
        s += v[j];
    }
    int orig = s;
    sh[t] = s;
    __syncthreads();
    for (int off = 1; off < 256; off <<= 1) {
        int u = (t >= off) ? sh[t - off] : 0;
        __syncthreads();
        sh[t] += u;
        __syncthreads();
    }
    int tbase = bsum[blockIdx.x] + sh[t] - orig;
#pragma unroll
    for (int j = 0; j < 4; ++j) {
        int idx = idx0 + j;
        if (idx < NN) {
            noffs[idx] = tbase;
            cursor[idx] = tbase;
        }
        tbase += v[j];
    }
    if (blockIdx.x == 0 && t == 0) noffs[NN] = EE;
}

// fill: pack (src | et<<24) into node-sorted order
__global__ void fill_kernel(const int* __restrict__ src, const int* __restrict__ dst,
                            const int* __restrict__ et, int* __restrict__ cursor,
                            unsigned* __restrict__ epack) {
    int e = blockIdx.x * blockDim.x + threadIdx.x;
    if (e >= EE) return;
    int pos = atomicAdd(&cursor[dst[e]], 1);
    epack[pos] = (unsigned)src[e] | ((unsigned)et[e] << 24);
}

// ---------------------------------------------------------------------------
// Basis-space aggregation: y[n,b,:] = sum_{e: dst=n} comp[et_e,b]/max(cnt[n,et_e],1) * x[src_e,:]
// 1 wave per node; edge packs prefetched 64 at a time and shfl-broadcast;
// row gathers unrolled x4 for MLP.
__global__ void aggregate_kernel(const float* __restrict__ x, const unsigned* __restrict__ epack,
                                 const int* __restrict__ noffs, const int* __restrict__ cnt,
                                 const float* __restrict__ comp, float* __restrict__ y) {
    __shared__ float wlds[4 * 32];  // [wave][r*4+b]
    int lane = threadIdx.x & 63;
    int wid = threadIdx.x >> 6;
    int n = blockIdx.x * 4 + wid;

    if (lane < 32) {
        int r = lane >> 2;
        float c = (float)cnt[n * 8 + r];
        wlds[wid * 32 + lane] = comp[lane] / fmaxf(c, 1.f);  // comp[r*4+b] == comp[lane]
    }
    __syncthreads();

    int s0 = noffs[n], s1 = noffs[n + 1];
    float a0 = 0.f, a1 = 0.f, a2 = 0.f, a3 = 0.f;

    for (int base = s0; base < s1; base += 64) {
        int m = s1 - base;
        if (m > 64) m = 64;
        unsigned pl = (base + lane < s1) ? epack[base + lane] : 0u;
        int k = 0;
        for (; k + 4 <= m; k += 4) {
            unsigned p0 = __shfl(pl, k), p1 = __shfl(pl, k + 1);
            unsigned p2 = __shfl(pl, k + 2), p3 = __shfl(pl, k + 3);
            float r0 = x[(size_t)(p0 & 0xFFFFFFu) * 64 + lane];
            float r1 = x[(size_t)(p1 & 0xFFFFFFu) * 64 + lane];
            float r2 = x[(size_t)(p2 & 0xFFFFFFu) * 64 + lane];
            float r3 = x[(size_t)(p3 & 0xFFFFFFu) * 64 + lane];
            float4 w0 = *reinterpret_cast<const float4*>(&wlds[wid * 32 + (p0 >> 24) * 4]);
            float4 w1 = *reinterpret_cast<const float4*>(&wlds[wid * 32 + (p1 >> 24) * 4]);
            float4 w2 = *reinterpret_cast<const float4*>(&wlds[wid * 32 + (p2 >> 24) * 4]);
            float4 w3 = *reinterpret_cast<const float4*>(&wlds[wid * 32 + (p3 >> 24) * 4]);
            a0 += w0.x * r0; a1 += w0.y * r0; a2 += w0.z * r0; a3 += w0.w * r0;
            a0 += w1.x * r1; a1 += w1.y * r1; a2 += w1.z * r1; a3 += w1.w * r1;
            a0 += w2.x * r2; a1 += w2.y * r2; a2 += w2.z * r2; a3 += w2.w * r2;
            a0 += w3.x * r3; a1 += w3.y * r3; a2 += w3.z * r3; a3 += w3.w * r3;
        }
        for (; k < m; ++k) {
            unsigned p = __shfl(pl, k);
            float r0 = x[(size_t)(p & 0xFFFFFFu) * 64 + lane];
            float4 w = *reinterpret_cast<const float4*>(&wlds[wid * 32 + (p >> 24) * 4]);
            a0 += w.x * r0; a1 += w.y * r0; a2 += w.z * r0; a3 += w.w * r0;
        }
    }

    size_t yb = (size_t)n * 256 + lane;
    y[yb] = a0; y[yb + 64] = a1; y[yb + 128] = a2; y[yb + 192] = a3;
}

// ---------------------------------------------------------------------------
// Transform: out[n,o] = bias[o] + sum_i x[n,i]*root[i,o] + sum_{b,i} y[n,b,i]*basis[b,i,o]
// PROJ variant (layer 2) additionally emits ha=z@W1[:64], hb=z@W1[64:] and skips z.
template <int RELU, int PROJ>
__global__ void combine_kernel(const float* __restrict__ xin, const float* __restrict__ y,
                               const float* __restrict__ basis, const float* __restrict__ root,
                               const float* __restrict__ bias, const float* __restrict__ W1,
                               float* __restrict__ out, float* __restrict__ ha,
                               float* __restrict__ hb) {
    __shared__ float xs[32 * 64];    // 8 KB
    __shared__ float ys[32 * 256];   // 32 KB
    int lane = threadIdx.x & 63;
    int wid = threadIdx.x >> 6;
    int nb = blockIdx.x * 32 + wid * 8;

#pragma unroll
    for (int q = 0; q < 8; ++q)
        xs[(wid * 8 + q) * 64 + lane] = xin[(size_t)(nb + q) * 64 + lane];
#pragma unroll
    for (int q = 0; q < 8; ++q)
#pragma unroll
        for (int b = 0; b < 4; ++b)
            ys[(wid * 8 + q) * 256 + b * 64 + lane] =
                y[(size_t)(nb + q) * 256 + b * 64 + lane];

    float bv = bias[lane];
    float acc[8];
#pragma unroll
    for (int q = 0; q < 8; ++q) acc[q] = bv;

    // root (self) transform
    for (int i = 0; i < 64; i += 4) {
        float4 f[8];
#pragma unroll
        for (int q = 0; q < 8; ++q)
            f[q] = *reinterpret_cast<const float4*>(&xs[(wid * 8 + q) * 64 + i]);
#pragma unroll
        for (int j = 0; j < 4; ++j) {
            float w = root[(i + j) * 64 + lane];
#pragma unroll
            for (int q = 0; q < 8; ++q)
                acc[q] += reinterpret_cast<const float*>(&f[q])[j] * w;
        }
    }

    // basis transforms
    for (int b = 0; b < 4; ++b) {
        const float* Bb = basis + b * 4096;
        for (int i = 0; i < 64; i += 4) {
            float4 f[8];
#pragma unroll
            for (int q = 0; q < 8; ++q)
                f[q] = *reinterpret_cast<const float4*>(&ys[(wid * 8 + q) * 256 + b * 64 + i]);
#pragma unroll
            for (int j = 0; j < 4; ++j) {
                float w = Bb[(i + j) * 64 + lane];
#pragma unroll
                for (int q = 0; q < 8; ++q)
                    acc[q] += reinterpret_cast<const float*>(&f[q])[j] * w;
            }
        }
    }

    if (!PROJ) {
#pragma unroll
        for (int q = 0; q < 8; ++q) {
            float v = acc[q];
            if (RELU) v = fmaxf(v, 0.f);
            out[(size_t)(nb + q) * 64 + lane] = v;
        }
    } else {
        // z lives only in LDS (per-wave region reuse of xs)
#pragma unroll
        for (int q = 0; q < 8; ++q)
            xs[(wid * 8 + q) * 64 + lane] = acc[q];

        float aA[8], aB[8];
#pragma unroll
        for (int q = 0; q < 8; ++q) { aA[q] = 0.f; aB[q] = 0.f; }
        for (int i = 0; i < 64; i += 4) {
            float4 f[8];
#pragma unroll
            for (int q = 0; q < 8; ++q)
                f[q] = *reinterpret_cast<const float4*>(&xs[(wid * 8 + q) * 64 + i]);
#pragma unroll
            for (int j = 0; j < 4; ++j) {
                float wA = W1[(i + j) * 64 + lane];
                float wB = W1[(i + j + 64) * 64 + lane];
#pragma unroll
                for (int q = 0; q < 8; ++q) {
                    float fv = reinterpret_cast<const float*>(&f[q])[j];
                    aA[q] += fv * wA;
                    aB[q] += fv * wB;
                }
            }
        }
#pragma unroll
        for (int q = 0; q < 8; ++q) {
            ha[(size_t)(nb + q) * 64 + lane] = aA[q];
            hb[(size_t)(nb + q) * 64 + lane] = aB[q];
        }
    }
}

// ---------------------------------------------------------------------------
// logit[p] = (relu(ha[a]+hb[b]+b1) . W2) + b2 — one wave per pair
__global__ void decode_kernel(const int* __restrict__ pairs, const float* __restrict__ ha,
                              const float* __restrict__ hb, const float* __restrict__ b1,
                              const float* __restrict__ W2, const float* __restrict__ b2,
                              float* __restrict__ out) {
    int lane = threadIdx.x & 63;
    int wid = threadIdx.x >> 6;
    int p = blockIdx.x * 4 + wid;
    if (p >= PP) return;
    int a = pairs[2 * p], b = pairs[2 * p + 1];
    float v = ha[(size_t)a * 64 + lane] + hb[(size_t)b * 64 + lane] + b1[lane];
    v = fmaxf(v, 0.f) * W2[lane];
#pragma unroll
    for (int off = 32; off >= 1; off >>= 1) v += __shfl_xor(v, off);
    if (lane == 0) out[p] = v + b2[0];
}

// ---------------------------------------------------------------------------
extern "C" void kernel_launch(void* const* d_in, const int* in_sizes, int n_in,
                              void* d_out, int out_size, void* d_ws, size_t ws_size,
                              hipStream_t stream) {
    const int* edge_index = (const int*)d_in[0];
    const int* edge_type  = (const int*)d_in[1];
    const int* edge_pairs = (const int*)d_in[2];
    const float* node_emb = (const float*)d_in[3];
    const float* comp1 = (const float*)d_in[4];
    const float* basis1 = (const float*)d_in[5];
    const float* root1 = (const float*)d_in[6];
    const float* bias1 = (const float*)d_in[7];
    const float* comp2 = (const float*)d_in[8];
    const float* basis2 = (const float*)d_in[9];
    const float* root2 = (const float*)d_in[10];
    const float* bias2 = (const float*)d_in[11];
    const float* W1 = (const float*)d_in[12];
    const float* b1 = (const float*)d_in[13];
    const float* W2 = (const float*)d_in[14];
    const float* b2 = (const float*)d_in[15];

    const int* src = edge_index;
    const int* dst = edge_index + EE;

    // workspace layout
    char* w = (char*)d_ws;
    int* cnt       = (int*)w;       w += sizeof(int) * (size_t)NN * RR;     // 3.2 MB
    int* deg       = (int*)w;       w += sizeof(int) * NN;
    int* bsum      = (int*)w;       w += sizeof(int) * 1024;
    int* noffs     = (int*)w;       w += sizeof(int) * (NN + 1);
    int* cursor    = (int*)w;       w += sizeof(int) * NN;
    unsigned* epack = (unsigned*)w; w += sizeof(unsigned) * EE;             // 8 MB
    float* y       = (float*)w;     w += sizeof(float) * (size_t)NN * 256;  // 102.4 MB
    float* x1      = (float*)w;     w += sizeof(float) * (size_t)NN * DD;   // 25.6 MB
    float* ha      = (float*)w;     w += sizeof(float) * (size_t)NN * DD;
    float* hb      = (float*)w;     w += sizeof(float) * (size_t)NN * DD;

    // ---- CSR build (node-level; shared by both layers) ----
    hipMemsetAsync(cnt, 0, sizeof(int) * (size_t)NN * RR, stream);
    count_kernel<<<(EE + 255) / 256, 256, 0, stream>>>(dst, edge_type, cnt);
    deg_kernel<<<(NN + 255) / 256, 256, 0, stream>>>(cnt, deg);
    scan_sums<<<NBLKN, 256, 0, stream>>>(deg, bsum);
    scan_partials<<<1, 1024, 0, stream>>>(bsum);
    scan_final<<<NBLKN, 256, 0, stream>>>(deg, bsum, noffs, cursor);
    fill_kernel<<<(EE + 255) / 256, 256, 0, stream>>>(src, dst, edge_type, cursor, epack);

    // ---- layer 1: node_emb -> x1 (relu) ----
    aggregate_kernel<<<NN / 4, 256, 0, stream>>>(node_emb, epack, noffs, cnt, comp1, y);
    combine_kernel<1, 0><<<NN / 32, 256, 0, stream>>>(node_emb, y, basis1, root1, bias1,
                                                      nullptr, x1, nullptr, nullptr);

    // ---- layer 2 (+decoder projection fused): x1 -> ha/hb ----
    aggregate_kernel<<<NN / 4, 256, 0, stream>>>(x1, epack, noffs, cnt, comp2, y);
    combine_kernel<0, 1><<<NN / 32, 256, 0, stream>>>(x1, y, basis2, root2, bias2,
                                                      W1, nullptr, ha, hb);

    // ---- decoder ----
    decode_kernel<<<PP / 4, 256, 0, stream>>>(edge_pairs, ha, hb, b1, W2, b2, (float*)d_out);
}

// Round 4
// 783.159 us; speedup vs baseline: 2.1427x; 1.6898x over previous
//
#include <hip/hip_runtime.h>

// Problem constants (fixed by the reference setup)
constexpr int NN = 100000;   // nodes
constexpr int RR = 8;        // relations
constexpr int BB = 4;        // bases
constexpr int DD = 64;       // feature dim
constexpr int EE = 2000000;  // edges
constexpr int PP = 500000;   // pairs

constexpr int SCAN_CHUNK = 1024;
constexpr int NBLKN = (NN + SCAN_CHUNK - 1) / SCAN_CHUNK;  // 98

// ---------------------------------------------------------------------------
// integer counts per (dst, relation) cell
__global__ void count_kernel(const int* __restrict__ dst, const int* __restrict__ et,
                             int* __restrict__ cnt) {
    int e = blockIdx.x * blockDim.x + threadIdx.x;
    if (e < EE) atomicAdd(&cnt[dst[e] * RR + et[e]], 1);
}

// node degree = sum of its 8 relation counts
__global__ void deg_kernel(const int* __restrict__ cnt, int* __restrict__ deg) {
    int n = blockIdx.x * blockDim.x + threadIdx.x;
    if (n >= NN) return;
    const int4* c = reinterpret_cast<const int4*>(cnt + n * 8);
    int4 a = c[0], b = c[1];
    deg[n] = a.x + a.y + a.z + a.w + b.x + b.y + b.z + b.w;
}

// K1: per-block sums of 1024-element chunks of deg
__global__ void scan_sums(const int* __restrict__ deg, int* __restrict__ bsum) {
    __shared__ int sh[256];
    int base = blockIdx.x * SCAN_CHUNK;
    int t = threadIdx.x;
    int s = 0;
    for (int i = t; i < SCAN_CHUNK; i += 256) {
        int idx = base + i;
        s += (idx < NN) ? deg[idx] : 0;
    }
    sh[t] = s;
    __syncthreads();
    for (int off = 128; off >= 1; off >>= 1) {
        if (t < off) sh[t] += sh[t + off];
        __syncthreads();
    }
    if (t == 0) bsum[blockIdx.x] = sh[0];
}

// K2: single-block exclusive scan of the NBLKN partials
__global__ void scan_partials(int* __restrict__ bsum) {
    __shared__ int sh[1024];
    int t = threadIdx.x;
    int orig = (t < NBLKN) ? bsum[t] : 0;
    sh[t] = orig;
    __syncthreads();
    for (int off = 1; off < 1024; off <<= 1) {
        int v = (t >= off) ? sh[t - off] : 0;
        __syncthreads();
        sh[t] += v;
        __syncthreads();
    }
    if (t < NBLKN) bsum[t] = sh[t] - orig;  // exclusive
}

// K3: final exclusive scan -> noffs[] and cursor[]
__global__ void scan_final(const int* __restrict__ deg, const int* __restrict__ bsum,
                           int* __restrict__ noffs, int* __restrict__ cursor) {
    __shared__ int sh[256];
    int base = blockIdx.x * SCAN_CHUNK;
    int t = threadIdx.x;
    int idx0 = base + t * 4;
    int v[4];
    int s = 0;
#pragma unroll
    for (int j = 0; j < 4; ++j) {
        int idx = idx0 + j;
        v[j] = (idx < NN) ? deg[idx] : 0;
        s += v[j];
    }
    int orig = s;
    sh[t] = s;
    __syncthreads();
    for (int off = 1; off < 256; off <<= 1) {
        int u = (t >= off) ? sh[t - off] : 0;
        __syncthreads();
        sh[t] += u;
        __syncthreads();
    }
    int tbase = bsum[blockIdx.x] + sh[t] - orig;
#pragma unroll
    for (int j = 0; j < 4; ++j) {
        int idx = idx0 + j;
        if (idx < NN) {
            noffs[idx] = tbase;
            cursor[idx] = tbase;
        }
        tbase += v[j];
    }
    if (blockIdx.x == 0 && t == 0) noffs[NN] = EE;
}

// fill: pack (src | et<<24) into node-sorted order
__global__ void fill_kernel(const int* __restrict__ src, const int* __restrict__ dst,
                            const int* __restrict__ et, int* __restrict__ cursor,
                            unsigned* __restrict__ epack) {
    int e = blockIdx.x * blockDim.x + threadIdx.x;
    if (e >= EE) return;
    int pos = atomicAdd(&cursor[dst[e]], 1);
    epack[pos] = (unsigned)src[e] | ((unsigned)et[e] << 24);
}

// ---------------------------------------------------------------------------
// Basis-space aggregation: y[n,b,:] = sum_{e: dst=n} comp[et_e,b]/max(cnt[n,et_e],1) * x[src_e,:]
__global__ void aggregate_kernel(const float* __restrict__ x, const unsigned* __restrict__ epack,
                                 const int* __restrict__ noffs, const int* __restrict__ cnt,
                                 const float* __restrict__ comp, float* __restrict__ y) {
    __shared__ float wlds[4 * 32];  // [wave][r*4+b]
    int lane = threadIdx.x & 63;
    int wid = threadIdx.x >> 6;
    int n = blockIdx.x * 4 + wid;

    if (lane < 32) {
        int r = lane >> 2;
        float c = (float)cnt[n * 8 + r];
        wlds[wid * 32 + lane] = comp[lane] / fmaxf(c, 1.f);  // comp[r*4+b] == comp[lane]
    }
    __syncthreads();

    int s0 = noffs[n], s1 = noffs[n + 1];
    float a0 = 0.f, a1 = 0.f, a2 = 0.f, a3 = 0.f;

    for (int base = s0; base < s1; base += 64) {
        int m = s1 - base;
        if (m > 64) m = 64;
        unsigned pl = (base + lane < s1) ? epack[base + lane] : 0u;
        int k = 0;
        for (; k + 4 <= m; k += 4) {
            unsigned p0 = __shfl(pl, k), p1 = __shfl(pl, k + 1);
            unsigned p2 = __shfl(pl, k + 2), p3 = __shfl(pl, k + 3);
            float r0 = x[(size_t)(p0 & 0xFFFFFFu) * 64 + lane];
            float r1 = x[(size_t)(p1 & 0xFFFFFFu) * 64 + lane];
            float r2 = x[(size_t)(p2 & 0xFFFFFFu) * 64 + lane];
            float r3 = x[(size_t)(p3 & 0xFFFFFFu) * 64 + lane];
            float4 w0 = *reinterpret_cast<const float4*>(&wlds[wid * 32 + (p0 >> 24) * 4]);
            float4 w1 = *reinterpret_cast<const float4*>(&wlds[wid * 32 + (p1 >> 24) * 4]);
            float4 w2 = *reinterpret_cast<const float4*>(&wlds[wid * 32 + (p2 >> 24) * 4]);
            float4 w3 = *reinterpret_cast<const float4*>(&wlds[wid * 32 + (p3 >> 24) * 4]);
            a0 += w0.x * r0; a1 += w0.y * r0; a2 += w0.z * r0; a3 += w0.w * r0;
            a0 += w1.x * r1; a1 += w1.y * r1; a2 += w1.z * r1; a3 += w1.w * r1;
            a0 += w2.x * r2; a1 += w2.y * r2; a2 += w2.z * r2; a3 += w2.w * r2;
            a0 += w3.x * r3; a1 += w3.y * r3; a2 += w3.z * r3; a3 += w3.w * r3;
        }
        for (; k < m; ++k) {
            unsigned p = __shfl(pl, k);
            float r0 = x[(size_t)(p & 0xFFFFFFu) * 64 + lane];
            float4 w = *reinterpret_cast<const float4*>(&wlds[wid * 32 + (p >> 24) * 4]);
            a0 += w.x * r0; a1 += w.y * r0; a2 += w.z * r0; a3 += w.w * r0;
        }
    }

    size_t yb = (size_t)n * 256 + lane;
    y[yb] = a0; y[yb + 64] = a1; y[yb + 128] = a2; y[yb + 192] = a3;
}

// ---------------------------------------------------------------------------
// One 64x64 f32 matmul accumulate step for 8 nodes staged in LDS.
// NOTE: no address of any register value is ever taken (scratch-spill-safe):
// float4 members accessed by name, acc[] indexed only by unrolled constants.
#define MM64(LDSBASE, STRIDE, WPTR)                                            \
    for (int i = 0; i < 64; i += 4) {                                          \
        float w0 = (WPTR)[(i + 0) * 64 + lane];                                \
        float w1 = (WPTR)[(i + 1) * 64 + lane];                                \
        float w2 = (WPTR)[(i + 2) * 64 + lane];                                \
        float w3 = (WPTR)[(i + 3) * 64 + lane];                                \
        _Pragma("unroll")                                                      \
        for (int q = 0; q < 8; ++q) {                                          \
            float4 f = *reinterpret_cast<const float4*>((LDSBASE) + q * (STRIDE) + i); \
            acc[q] = fmaf(f.x, w0, acc[q]);                                    \
            acc[q] = fmaf(f.y, w1, acc[q]);                                    \
            acc[q] = fmaf(f.z, w2, acc[q]);                                    \
            acc[q] = fmaf(f.w, w3, acc[q]);                                    \
        }                                                                      \
    }

// Transform: out[n,o] = bias[o] + sum_i x[n,i]*root[i,o] + sum_{b,i} y[n,b,i]*basis[b,i,o]
// PROJ variant (layer 2) additionally emits ha=z@W1[:64], hb=z@W1[64:] and skips z.
template <int RELU, int PROJ>
__global__ void combine_kernel(const float* __restrict__ xin, const float* __restrict__ y,
                               const float* __restrict__ basis, const float* __restrict__ root,
                               const float* __restrict__ bias, const float* __restrict__ W1,
                               float* __restrict__ out, float* __restrict__ ha,
                               float* __restrict__ hb) {
    __shared__ float xs[32 * 64];    // 8 KB
    __shared__ float ys[32 * 256];   // 32 KB
    int lane = threadIdx.x & 63;
    int wid = threadIdx.x >> 6;
    int nb = blockIdx.x * 32 + wid * 8;

#pragma unroll
    for (int q = 0; q < 8; ++q)
        xs[(wid * 8 + q) * 64 + lane] = xin[(size_t)(nb + q) * 64 + lane];
#pragma unroll
    for (int q = 0; q < 8; ++q)
#pragma unroll
        for (int b = 0; b < 4; ++b)
            ys[(wid * 8 + q) * 256 + b * 64 + lane] =
                y[(size_t)(nb + q) * 256 + b * 64 + lane];

    float bv = bias[lane];
    float acc[8];
#pragma unroll
    for (int q = 0; q < 8; ++q) acc[q] = bv;

    const float* xbase = &xs[wid * 8 * 64];
    const float* ybase = &ys[wid * 8 * 256];

    // root (self) transform
    MM64(xbase, 64, root)
    // basis transforms
    MM64(ybase + 0 * 64, 256, basis + 0 * 4096)
    MM64(ybase + 1 * 64, 256, basis + 1 * 4096)
    MM64(ybase + 2 * 64, 256, basis + 2 * 4096)
    MM64(ybase + 3 * 64, 256, basis + 3 * 4096)

    if (!PROJ) {
#pragma unroll
        for (int q = 0; q < 8; ++q) {
            float v = acc[q];
            if (RELU) v = fmaxf(v, 0.f);
            out[(size_t)(nb + q) * 64 + lane] = v;
        }
    } else {
        // z lives only in LDS (per-wave region reuse of xs)
#pragma unroll
        for (int q = 0; q < 8; ++q)
            xs[(wid * 8 + q) * 64 + lane] = acc[q];

        float aA[8], aB[8];
#pragma unroll
        for (int q = 0; q < 8; ++q) { aA[q] = 0.f; aB[q] = 0.f; }
        for (int i = 0; i < 64; i += 4) {
            float wA0 = W1[(i + 0) * 64 + lane];
            float wA1 = W1[(i + 1) * 64 + lane];
            float wA2 = W1[(i + 2) * 64 + lane];
            float wA3 = W1[(i + 3) * 64 + lane];
            float wB0 = W1[(i + 64) * 64 + lane];
            float wB1 = W1[(i + 65) * 64 + lane];
            float wB2 = W1[(i + 66) * 64 + lane];
            float wB3 = W1[(i + 67) * 64 + lane];
#pragma unroll
            for (int q = 0; q < 8; ++q) {
                float4 f = *reinterpret_cast<const float4*>(xbase + q * 64 + i);
                aA[q] = fmaf(f.x, wA0, aA[q]);
                aA[q] = fmaf(f.y, wA1, aA[q]);
                aA[q] = fmaf(f.z, wA2, aA[q]);
                aA[q] = fmaf(f.w, wA3, aA[q]);
                aB[q] = fmaf(f.x, wB0, aB[q]);
                aB[q] = fmaf(f.y, wB1, aB[q]);
                aB[q] = fmaf(f.z, wB2, aB[q]);
                aB[q] = fmaf(f.w, wB3, aB[q]);
            }
        }
#pragma unroll
        for (int q = 0; q < 8; ++q) {
            ha[(size_t)(nb + q) * 64 + lane] = aA[q];
            hb[(size_t)(nb + q) * 64 + lane] = aB[q];
        }
    }
}

// ---------------------------------------------------------------------------
// logit[p] = (relu(ha[a]+hb[b]+b1) . W2) + b2 — one wave per pair
__global__ void decode_kernel(const int* __restrict__ pairs, const float* __restrict__ ha,
                              const float* __restrict__ hb, const float* __restrict__ b1,
                              const float* __restrict__ W2, const float* __restrict__ b2,
                              float* __restrict__ out) {
    int lane = threadIdx.x & 63;
    int wid = threadIdx.x >> 6;
    int p = blockIdx.x * 4 + wid;
    if (p >= PP) return;
    int a = pairs[2 * p], b = pairs[2 * p + 1];
    float v = ha[(size_t)a * 64 + lane] + hb[(size_t)b * 64 + lane] + b1[lane];
    v = fmaxf(v, 0.f) * W2[lane];
#pragma unroll
    for (int off = 32; off >= 1; off >>= 1) v += __shfl_xor(v, off);
    if (lane == 0) out[p] = v + b2[0];
}

// ---------------------------------------------------------------------------
extern "C" void kernel_launch(void* const* d_in, const int* in_sizes, int n_in,
                              void* d_out, int out_size, void* d_ws, size_t ws_size,
                              hipStream_t stream) {
    const int* edge_index = (const int*)d_in[0];
    const int* edge_type  = (const int*)d_in[1];
    const int* edge_pairs = (const int*)d_in[2];
    const float* node_emb = (const float*)d_in[3];
    const float* comp1 = (const float*)d_in[4];
    const float* basis1 = (const float*)d_in[5];
    const float* root1 = (const float*)d_in[6];
    const float* bias1 = (const float*)d_in[7];
    const float* comp2 = (const float*)d_in[8];
    const float* basis2 = (const float*)d_in[9];
    const float* root2 = (const float*)d_in[10];
    const float* bias2 = (const float*)d_in[11];
    const float* W1 = (const float*)d_in[12];
    const float* b1 = (const float*)d_in[13];
    const float* W2 = (const float*)d_in[14];
    const float* b2 = (const float*)d_in[15];

    const int* src = edge_index;
    const int* dst = edge_index + EE;

    // workspace layout
    char* w = (char*)d_ws;
    int* cnt       = (int*)w;       w += sizeof(int) * (size_t)NN * RR;     // 3.2 MB
    int* deg       = (int*)w;       w += sizeof(int) * NN;
    int* bsum      = (int*)w;       w += sizeof(int) * 1024;
    int* noffs     = (int*)w;       w += sizeof(int) * (NN + 1);
    int* cursor    = (int*)w;       w += sizeof(int) * NN;
    unsigned* epack = (unsigned*)w; w += sizeof(unsigned) * EE;             // 8 MB
    float* y       = (float*)w;     w += sizeof(float) * (size_t)NN * 256;  // 102.4 MB
    float* x1      = (float*)w;     w += sizeof(float) * (size_t)NN * DD;   // 25.6 MB
    float* ha      = (float*)w;     w += sizeof(float) * (size_t)NN * DD;
    float* hb      = (float*)w;     w += sizeof(float) * (size_t)NN * DD;

    // ---- CSR build (node-level; shared by both layers) ----
    hipMemsetAsync(cnt, 0, sizeof(int) * (size_t)NN * RR, stream);
    count_kernel<<<(EE + 255) / 256, 256, 0, stream>>>(dst, edge_type, cnt);
    deg_kernel<<<(NN + 255) / 256, 256, 0, stream>>>(cnt, deg);
    scan_sums<<<NBLKN, 256, 0, stream>>>(deg, bsum);
    scan_partials<<<1, 1024, 0, stream>>>(bsum);
    scan_final<<<NBLKN, 256, 0, stream>>>(deg, bsum, noffs, cursor);
    fill_kernel<<<(EE + 255) / 256, 256, 0, stream>>>(src, dst, edge_type, cursor, epack);

    // ---- layer 1: node_emb -> x1 (relu) ----
    aggregate_kernel<<<NN / 4, 256, 0, stream>>>(node_emb, epack, noffs, cnt, comp1, y);
    combine_kernel<1, 0><<<NN / 32, 256, 0, stream>>>(node_emb, y, basis1, root1, bias1,
                                                      nullptr, x1, nullptr, nullptr);

    // ---- layer 2 (+decoder projection fused): x1 -> ha/hb ----
    aggregate_kernel<<<NN / 4, 256, 0, stream>>>(x1, epack, noffs, cnt, comp2, y);
    combine_kernel<0, 1><<<NN / 32, 256, 0, stream>>>(x1, y, basis2, root2, bias2,
                                                      W1, nullptr, ha, hb);

    // ---- decoder ----
    decode_kernel<<<PP / 4, 256, 0, stream>>>(edge_pairs, ha, hb, b1, W2, b2, (float*)d_out);
}